// Round 2
// baseline (69.286 us; speedup 1.0000x reference)
//
#include <hip/hip_runtime.h>
#include <cstdint>
#include <cstddef>

#define TINV 5.0f
#define C5L2E 7.2134752044448170f   // 5 * log2(e)
#define NROWS 4096
#define DDIM 256
#define MM 8192
#define BM 128
#define BN 128
#define NCS 8
#define COLS_PER_SPLIT 1024
#define TILES_PER_SPLIT 8

typedef __bf16 bf16x8 __attribute__((ext_vector_type(8)));
typedef float f32x4 __attribute__((ext_vector_type(4)));

typedef const void __attribute__((address_space(1)))* gas_ptr;
typedef void __attribute__((address_space(3)))* las_ptr;

// ---------------- normalize: rows of [Z1;Z2] -> unit L2, store bf16 ----------------
__global__ __launch_bounds__(256, 2)
void nrm_kernel(const float* __restrict__ Z1, const float* __restrict__ Z2,
                unsigned short* __restrict__ Zb) {
    const int w = threadIdx.x >> 6, lane = threadIdx.x & 63;
    const int row = blockIdx.x * 4 + w;
    const float* src = row < NROWS ? Z1 + (size_t)row * DDIM
                                   : Z2 + (size_t)(row - NROWS) * DDIM;
    float4 v = reinterpret_cast<const float4*>(src)[lane];
    float ss = v.x*v.x + v.y*v.y + v.z*v.z + v.w*v.w;
    #pragma unroll
    for (int m = 1; m < 64; m <<= 1) ss += __shfl_xor(ss, m, 64);
    float inv = 1.0f / fmaxf(sqrtf(ss), 1e-12f);
    float o[4] = { v.x*inv, v.y*inv, v.z*inv, v.w*inv };
    unsigned short us[4];
    #pragma unroll
    for (int e = 0; e < 4; ++e) {           // RNE f32->bf16 (finite inputs)
        unsigned int b = __builtin_bit_cast(unsigned int, o[e]);
        b += 0x7FFFu + ((b >> 16) & 1u);
        us[e] = (unsigned short)(b >> 16);
    }
    reinterpret_cast<ushort4*>(Zb + (size_t)row * DDIM)[lane] =
        *reinterpret_cast<ushort4*>(us);
}

// ---- stage 128 rows x 256 cols bf16 (64KB contiguous) into LDS, XOR-swizzled ----
// LDS dest is linear (global_load_lds requirement); global SOURCE is pre-swizzled
// so that reads with phys = lin ^ ((row&7)<<4) see the correct data.
__device__ __forceinline__ void stage_tile(const unsigned short* Zb, unsigned short* lds,
                                           int rowStart, int tid) {
    const char* base = reinterpret_cast<const char*>(Zb) + (size_t)rowStart * 512;
    char* lb = reinterpret_cast<char*>(lds);
    #pragma unroll
    for (int it = 0; it < 16; ++it) {
        int L = it * 4096 + tid * 16;     // linear LDS byte offset, lane-contiguous
        int row = L >> 9;                 // 0..127 (512 B per row)
        int inrow = L & 511;
        int soff = row * 512 + (inrow ^ ((row & 7) << 4));
        __builtin_amdgcn_global_load_lds((gas_ptr)(base + soff), (las_ptr)(lb + L),
                                         16, 0, 0);
    }
}

// fragment read: lane holds row (lane&15) of the 16-row subtile, k = (lane>>4)*8 + kk*32 .. +8
__device__ __forceinline__ bf16x8 lds_frag(const unsigned short* lds, int row, int kk, int lane) {
    int kbyte = ((lane >> 4) << 4) + (kk << 6);
    int phys = (row * 512 + kbyte) ^ ((row & 7) << 4);
    return *reinterpret_cast<const bf16x8*>(reinterpret_cast<const char*>(lds) + phys);
}

// ---------------- fused sim + online sum-exp + pos extraction ----------------
__global__ __launch_bounds__(256, 2)
void sim_lse_kernel(const unsigned short* __restrict__ Zb,
                    float* __restrict__ partials,   // [NCS][MM]
                    float* __restrict__ posArr) {   // [MM]
    __shared__ unsigned short ldsT[BM * DDIM];      // 64 KB
    const int tid = threadIdx.x;
    const int lane = tid & 63;
    const int w = tid >> 6;                         // wave 0..3, owns 32 rows
    const int rt = blockIdx.x >> 3;                 // row tile 0..63
    const int cs = blockIdx.x & 7;                  // col split 0..7
    const int R0 = rt * BM;

    // stage Q rows once, pull A-fragments into registers (full K=256)
    stage_tile(Zb, ldsT, R0, tid);
    __syncthreads();
    bf16x8 qf[2][8];
    #pragma unroll
    for (int mf = 0; mf < 2; ++mf)
        #pragma unroll
        for (int kk = 0; kk < 8; ++kk)
            qf[mf][kk] = lds_frag(ldsT, w * 32 + mf * 16 + (lane & 15), kk, lane);
    __syncthreads();

    float rowsum[2][4] = {{0.f,0.f,0.f,0.f},{0.f,0.f,0.f,0.f}};
    const int iBase = R0 + w * 32 + ((lane >> 4) << 2);  // C/D: row=(lane>>4)*4+r

    for (int ct = 0; ct < TILES_PER_SPLIT; ++ct) {
        const int C0 = cs * COLS_PER_SPLIT + ct * BN;
        stage_tile(Zb, ldsT, C0, tid);
        __syncthreads();
        for (int nf = 0; nf < 8; ++nf) {
            f32x4 acc0 = {0.f,0.f,0.f,0.f}, acc1 = {0.f,0.f,0.f,0.f};
            #pragma unroll
            for (int kk = 0; kk < 8; ++kk) {
                bf16x8 b = lds_frag(ldsT, nf * 16 + (lane & 15), kk, lane);
                acc0 = __builtin_amdgcn_mfma_f32_16x16x32_bf16(qf[0][kk], b, acc0, 0, 0, 0);
                acc1 = __builtin_amdgcn_mfma_f32_16x16x32_bf16(qf[1][kk], b, acc1, 0, 0, 0);
            }
            const int j = C0 + nf * 16 + (lane & 15);    // C/D: col=lane&15
            #pragma unroll
            for (int mf = 0; mf < 2; ++mf) {
                const f32x4 a = mf ? acc1 : acc0;
                #pragma unroll
                for (int r = 0; r < 4; ++r) {
                    const int i = iBase + mf * 16 + r;
                    const int pc = i < NROWS ? i + NROWS : i - NROWS;
                    // exp(sim - 5) = 2^(a*5*log2e - 5*log2e); skip diagonal
                    if (j != i) rowsum[mf][r] += __builtin_amdgcn_exp2f(fmaf(a[r], C5L2E, -C5L2E));
                    if (j == pc) posArr[i] = a[r] * TINV;  // unique writer
                }
            }
        }
        __syncthreads();
    }

    // reduce partial row-sums across the 16 lanes sharing each row
    #pragma unroll
    for (int mf = 0; mf < 2; ++mf)
        #pragma unroll
        for (int r = 0; r < 4; ++r) {
            float s = rowsum[mf][r];
            s += __shfl_xor(s, 1, 64);
            s += __shfl_xor(s, 2, 64);
            s += __shfl_xor(s, 4, 64);
            s += __shfl_xor(s, 8, 64);
            if ((lane & 15) == 0)
                partials[cs * MM + iBase + mf * 16 + r] = s;  // unique slot
        }
}

// ---------------- final: lse = log(sum) + 5; mean(lse - pos) ----------------
__global__ __launch_bounds__(256)
void fin_kernel(const float* __restrict__ partials, const float* __restrict__ posArr,
                float* __restrict__ out) {
    const int tid = threadIdx.x;
    double local = 0.0;
    for (int i = tid; i < MM; i += 256) {
        float se = 0.f;
        #pragma unroll
        for (int c = 0; c < NCS; ++c) se += partials[c * MM + i];
        float lse = logf(se) + 5.0f;
        local += (double)(lse - posArr[i]);
    }
    #pragma unroll
    for (int m = 1; m < 64; m <<= 1) local += __shfl_xor(local, m, 64);
    __shared__ double red[4];
    const int w = tid >> 6, lane = tid & 63;
    if (lane == 0) red[w] = local;
    __syncthreads();
    if (tid == 0) out[0] = (float)((red[0] + red[1] + red[2] + red[3]) / (double)MM);
}

extern "C" void kernel_launch(void* const* d_in, const int* in_sizes, int n_in,
                              void* d_out, int out_size, void* d_ws, size_t ws_size,
                              hipStream_t stream) {
    const float* Z1 = (const float*)d_in[0];
    const float* Z2 = (const float*)d_in[1];
    float* out = (float*)d_out;
    char* ws = (char*)d_ws;
    unsigned short* Zb = (unsigned short*)ws;                       // 4 MB bf16 [8192][256]
    float* posArr = (float*)(ws + (size_t)MM * DDIM * 2);           // 32 KB
    float* partials = (float*)(ws + (size_t)MM * DDIM * 2 + MM * 4); // 256 KB

    nrm_kernel<<<MM / 4, 256, 0, stream>>>(Z1, Z2, Zb);
    sim_lse_kernel<<<64 * NCS, 256, 0, stream>>>(Zb, partials, posArr);
    fin_kernel<<<1, 256, 0, stream>>>(partials, posArr, out);
}